// Round 10
// baseline (1037.620 us; speedup 1.0000x reference)
//
#include <hip/hip_runtime.h>
#include <hip/hip_bf16.h>
#include <hip/hip_cooperative_groups.h>

#define NV 4096
#define NE 8192
#define AD 64      // ATOM_DIM
#define BD 32      // BOND_DIM_P1
#define HD 128     // H
#define NL 4       // N_LAYER

#define BLK 256

// Everything is fp32 (proven r6-r8).

__device__ __forceinline__ float leaky(float x) { return x > 0.f ? x : 0.01f * x; }
__device__ __forceinline__ int clampv(int x) { return min(max(x, 0), NV - 1); }

// ---- fp32 weight scratch layout (float offsets), proven r3/r6-r8 ----
#define W_VW1T 0           // [64][128]   Wt[k][j] = W[j][k]
#define W_VW2T 8192        // [128][128]
#define W_EW1T 24576       // [32][128]
#define W_EW2T 28672       // [128][128]
#define W_MWT  45056       // [4][128][128]
#define W_VB1  110592
#define W_VB2  110720
#define W_EB1  110848
#define W_EB2  110976
#define W_MB   111104      // [4][128]
#define W_TOTAL 111616     // = 436 * 256 exactly

// ---- out layout (float offsets): [hv 524288][per-edge 384: src|dst|he] ----
#define OUT_HE 524288
#define ESTR   384

struct MegaParams {
    const uint4* vew1; const uint4* vew2;
    const float* atom; const float* bond;
    const float* vW1; const float* vW2; const float* eW1; const float* eW2;
    const float* mW;
    const float* vb1; const float* vb2; const float* eb1; const float* eb2;
    const float* mb;
    int* srcv; int* dstv;
    float* wb; float* hv; float* acc; float* outf;
};

// micro-GEMM (proven r3/r6-r8)
template<int K>
__device__ __forceinline__ float4 gemm_row(const float* __restrict__ xrow,
                                           const float* __restrict__ Wt, int jg) {
    float4 c = make_float4(0.f, 0.f, 0.f, 0.f);
    const float4* W4 = (const float4*)Wt;
#pragma unroll 8
    for (int k = 0; k < K; k += 4) {
        float4 xv = *(const float4*)(xrow + k);
        float4 w0 = W4[(k + 0) * 32 + jg];
        float4 w1 = W4[(k + 1) * 32 + jg];
        float4 w2 = W4[(k + 2) * 32 + jg];
        float4 w3 = W4[(k + 3) * 32 + jg];
        c.x = fmaf(xv.x, w0.x, fmaf(xv.y, w1.x, fmaf(xv.z, w2.x, fmaf(xv.w, w3.x, c.x))));
        c.y = fmaf(xv.x, w0.y, fmaf(xv.y, w1.y, fmaf(xv.z, w2.y, fmaf(xv.w, w3.y, c.y))));
        c.z = fmaf(xv.x, w0.z, fmaf(xv.y, w1.z, fmaf(xv.z, w2.z, fmaf(xv.w, w3.z, c.z))));
        c.w = fmaf(xv.x, w0.w, fmaf(xv.y, w1.w, fmaf(xv.z, w2.w, fmaf(xv.w, w3.w, c.w))));
    }
    return c;
}

// ---------------------------------------------------------------------------
// Cooperative mega-kernel. Grid-size-agnostic (block/thread-stride phases);
// grid is sized by the host from a runtime occupancy query so the coop
// launch's co-residency validation cannot reject it.
// ---------------------------------------------------------------------------
__global__ __launch_bounds__(BLK) void mega_k(MegaParams P) {
    namespace cg = cooperative_groups;
    cg::grid_group grid = cg::this_grid();
    __shared__ __align__(16) float xs[8 * HD];   // 4 KB
    __shared__ __align__(16) float t1[8 * HD];   // 4 KB
    const int t = threadIdx.x;
    const int NB = gridDim.x;
    const long NT = (long)NB * BLK;
    const long tid = (long)blockIdx.x * BLK + t;
    const int jg = t & 31, rg = t >> 5, j0 = jg * 4;

    // ---- Phase 0: extract src/dst + weight prep (r8-proven bodies) ----
    for (int w = blockIdx.x; w < 2484; w += NB) {
        if (w < 2048) {
            const uint4* m = (w < 1024) ? P.vew1 : P.vew2;
            int* out = (w < 1024) ? P.srcv : P.dstv;
            int r0 = (w & 1023) * 4;
            const uint4* p = m + (long)r0 * 2048;
#pragma unroll
            for (int b = 0; b < 2; b++) {
                uint4 u[16];
                unsigned o[16];
                int base = b * 4096 + t;
#pragma unroll
                for (int k = 0; k < 16; k++) u[k] = p[base + k * 256];
#pragma unroll
                for (int k = 0; k < 16; k++) o[k] = u[k].x | u[k].y | u[k].z | u[k].w;
                unsigned any = 0;
#pragma unroll
                for (int k = 0; k < 16; k++) any |= o[k];
                if (any == 0u) continue;
#pragma unroll
                for (int k = 0; k < 16; k++) {
                    if (o[k] == 0u) continue;
                    int i = base + k * 256;
                    int row = r0 + (i >> 11);
                    int col = (i << 2) & (NE - 1);
                    if (u[k].x) out[col + 0] = row;
                    if (u[k].y) out[col + 1] = row;
                    if (u[k].z) out[col + 2] = row;
                    if (u[k].w) out[col + 3] = row;
                }
            }
        } else {
            int i = (w - 2048) * 256 + t;
            if (i < W_TOTAL) {
                float v;
                if (i < W_VW2T)      { int q = i;          int k = q / 128, j = q % 128; v = P.vW1[(long)j * AD + k]; }
                else if (i < W_EW1T) { int q = i - W_VW2T; int k = q / 128, j = q % 128; v = P.vW2[(long)j * HD + k]; }
                else if (i < W_EW2T) { int q = i - W_EW1T; int k = q / 128, j = q % 128; v = P.eW1[(long)j * BD + k]; }
                else if (i < W_MWT)  { int q = i - W_EW2T; int k = q / 128, j = q % 128; v = P.eW2[(long)j * HD + k]; }
                else if (i < W_VB1)  { int q = i - W_MWT;  int l = q / 16384, r = q % 16384;
                                       int k = r / 128, j = r % 128;
                                       v = P.mW[(long)l * 16384 + (long)j * HD + k]; }
                else if (i < W_VB2)  v = P.vb1[i - W_VB1];
                else if (i < W_EB1)  v = P.vb2[i - W_VB2];
                else if (i < W_EB2)  v = P.eb1[i - W_EB1];
                else if (i < W_MB)   v = P.eb2[i - W_EB2];
                else                 v = P.mb[i - W_MB];
                P.wb[i] = v;
            }
        }
    }
    __threadfence();
    grid.sync();

    // ---- Phase A: input MLPs. units [0,512): 8 node rows; [512,1536): 8 edge rows ----
    for (int u = blockIdx.x; u < 1536; u += NB) {
        if (u < 512) {
            int r0 = u * 8;
            for (int i = t; i < 8 * AD; i += BLK) xs[i] = P.atom[(long)r0 * AD + i];
            __syncthreads();
            float4 c1 = gemm_row<AD>(xs + rg * AD, P.wb + W_VW1T, jg);
            float4 b1 = *(const float4*)(P.wb + W_VB1 + j0);
            c1.x = leaky(c1.x + b1.x); c1.y = leaky(c1.y + b1.y);
            c1.z = leaky(c1.z + b1.z); c1.w = leaky(c1.w + b1.w);
            *(float4*)(t1 + rg * HD + j0) = c1;
            __syncthreads();
            float4 c2 = gemm_row<HD>(t1 + rg * HD, P.wb + W_VW2T, jg);
            float4 b2 = *(const float4*)(P.wb + W_VB2 + j0);
            c2.x = tanhf(c2.x + b2.x); c2.y = tanhf(c2.y + b2.y);
            c2.z = tanhf(c2.z + b2.z); c2.w = tanhf(c2.w + b2.w);
            long o = (long)(r0 + rg) * HD + j0;
            *(float4*)(P.hv + o) = c2;
            *(float4*)(P.acc + o) = c2;
            __syncthreads();
        } else {
            int r0 = (u - 512) * 8;
            for (int i = t; i < 8 * BD; i += BLK) xs[i] = P.bond[(long)r0 * BD + i];
            __syncthreads();
            float4 c1 = gemm_row<BD>(xs + rg * BD, P.wb + W_EW1T, jg);
            float4 b1 = *(const float4*)(P.wb + W_EB1 + j0);
            c1.x = leaky(c1.x + b1.x); c1.y = leaky(c1.y + b1.y);
            c1.z = leaky(c1.z + b1.z); c1.w = leaky(c1.w + b1.w);
            *(float4*)(t1 + rg * HD + j0) = c1;
            __syncthreads();
            float4 c2 = gemm_row<HD>(t1 + rg * HD, P.wb + W_EW2T, jg);
            float4 b2 = *(const float4*)(P.wb + W_EB2 + j0);
            c2.x = tanhf(c2.x + b2.x); c2.y = tanhf(c2.y + b2.y);
            c2.z = tanhf(c2.z + b2.z); c2.w = tanhf(c2.w + b2.w);
            *(float4*)(P.outf + (long)OUT_HE + (long)(r0 + rg) * ESTR + 2 * HD + j0) = c2;
            __syncthreads();
        }
    }
    __threadfence();
    grid.sync();

    // ---- 4 message-passing layers ----
    for (int l = 0; l < NL; l++) {
        // Phase B: acc[src[e]] += relu(he[e] + hv[dst[e]])
        for (long idx = tid; idx < (long)NE * HD; idx += NT) {
            int e = (int)(idx >> 7), j = (int)(idx & 127);
            int s = clampv(P.srcv[e]), d = clampv(P.dstv[e]);
            float v = P.outf[(long)OUT_HE + (long)e * ESTR + 2 * HD + j]
                      + P.hv[(long)d * HD + j];
            v = v > 0.f ? v : 0.f;
            atomicAdd(P.acc + (long)s * HD + j, v);
        }
        __threadfence();
        grid.sync();

        // Phase C: hv = leaky(acc @ W[l].T + b[l]); acc = hv; l==3 -> out hv
        for (int u = blockIdx.x; u < 512; u += NB) {
            int r0 = u * 8;
            for (int i = t; i < 8 * HD; i += BLK) xs[i] = P.acc[(long)r0 * HD + i];
            __syncthreads();
            float4 c = gemm_row<HD>(xs + rg * HD, P.wb + W_MWT + l * 16384, jg);
            float4 b = *(const float4*)(P.wb + W_MB + l * HD + j0);
            c.x = leaky(c.x + b.x); c.y = leaky(c.y + b.y);
            c.z = leaky(c.z + b.z); c.w = leaky(c.w + b.w);
            long o = (long)(r0 + rg) * HD + j0;
            *(float4*)(P.hv + o) = c;
            *(float4*)(P.acc + o) = c;
            if (l == NL - 1) *(float4*)(P.outf + o) = c;
            __syncthreads();
        }
        __threadfence();
        grid.sync();
    }

    // ---- Phase D: gather sections out[e] = [hv[src]|hv[dst]|he(in place)] ----
    for (long idx = tid; idx < (long)NE * 64; idx += NT) {
        int e = (int)(idx >> 6), lane = (int)(idx & 63);
        int jj = lane * 2;
        int s = clampv(P.srcv[e]), d = clampv(P.dstv[e]);
        float2 a = *(const float2*)(P.hv + (long)s * HD + jj);
        float2 b = *(const float2*)(P.hv + (long)d * HD + jj);
        float* base = P.outf + (long)OUT_HE + (long)e * ESTR;
        *(float2*)(base + jj) = a;
        *(float2*)(base + HD + jj) = b;
    }
}

// ===========================================================================
// Fallback path: r8-proven kernels, launched only if the cooperative launch
// is rejected by the runtime (deterministic per device -> same work per call).
// ===========================================================================
__global__ __launch_bounds__(256, 3)
void extract_prep_k(const uint4* __restrict__ vew1, const uint4* __restrict__ vew2,
                    int* __restrict__ srcv, int* __restrict__ dstv,
                    const float* __restrict__ vW1, const float* __restrict__ vW2,
                    const float* __restrict__ eW1, const float* __restrict__ eW2,
                    const float* __restrict__ mW,
                    const float* __restrict__ vb1, const float* __restrict__ vb2,
                    const float* __restrict__ eb1, const float* __restrict__ eb2,
                    const float* __restrict__ mb, float* __restrict__ wb) {
    int blk = blockIdx.x, t = threadIdx.x;
    if (blk < 2048) {
        const uint4* m = (blk < 1024) ? vew1 : vew2;
        int* out = (blk < 1024) ? srcv : dstv;
        int r0 = (blk & 1023) * 4;
        const uint4* p = m + (long)r0 * 2048;
#pragma unroll
        for (int b = 0; b < 2; b++) {
            uint4 u[16];
            unsigned o[16];
            int base = b * 4096 + t;
#pragma unroll
            for (int k = 0; k < 16; k++) u[k] = p[base + k * 256];
#pragma unroll
            for (int k = 0; k < 16; k++) o[k] = u[k].x | u[k].y | u[k].z | u[k].w;
            unsigned any = 0;
#pragma unroll
            for (int k = 0; k < 16; k++) any |= o[k];
            if (any == 0u) continue;
#pragma unroll
            for (int k = 0; k < 16; k++) {
                if (o[k] == 0u) continue;
                int i = base + k * 256;
                int row = r0 + (i >> 11);
                int col = (i << 2) & (NE - 1);
                if (u[k].x) out[col + 0] = row;
                if (u[k].y) out[col + 1] = row;
                if (u[k].z) out[col + 2] = row;
                if (u[k].w) out[col + 3] = row;
            }
        }
    } else {
        int i = (blk - 2048) * 256 + t;
        if (i >= W_TOTAL) return;
        float v;
        if (i < W_VW2T)      { int q = i;          int k = q / 128, j = q % 128; v = vW1[(long)j * AD + k]; }
        else if (i < W_EW1T) { int q = i - W_VW2T; int k = q / 128, j = q % 128; v = vW2[(long)j * HD + k]; }
        else if (i < W_EW2T) { int q = i - W_EW1T; int k = q / 128, j = q % 128; v = eW1[(long)j * BD + k]; }
        else if (i < W_MWT)  { int q = i - W_EW2T; int k = q / 128, j = q % 128; v = eW2[(long)j * HD + k]; }
        else if (i < W_VB1)  { int q = i - W_MWT;  int l = q / 16384, r = q % 16384;
                               int k = r / 128, j = r % 128;
                               v = mW[(long)l * 16384 + (long)j * HD + k]; }
        else if (i < W_VB2)  v = vb1[i - W_VB1];
        else if (i < W_EB1)  v = vb2[i - W_VB2];
        else if (i < W_EB2)  v = eb1[i - W_EB1];
        else if (i < W_MB)   v = eb2[i - W_EB2];
        else                 v = mb[i - W_MB];
        wb[i] = v;
    }
}

__global__ void vlin_elin_k(const float* __restrict__ atom, const float* __restrict__ bond,
                            const float* __restrict__ wb,
                            float* __restrict__ hv, float* __restrict__ acc,
                            float* __restrict__ outf) {
    __shared__ __align__(16) float xs[4 * AD];
    __shared__ __align__(16) float t1[4 * HD];
    int t = threadIdx.x, jg = t & 31, rg = t >> 5, j0 = jg * 4;
    if (blockIdx.x < NV / 4) {
        int r0 = blockIdx.x * 4;
        for (int i = t; i < 4 * AD; i += 128) xs[i] = atom[(long)r0 * AD + i];
        __syncthreads();
        float4 c1 = gemm_row<AD>(xs + rg * AD, wb + W_VW1T, jg);
        float4 b1 = *(const float4*)(wb + W_VB1 + j0);
        c1.x = leaky(c1.x + b1.x); c1.y = leaky(c1.y + b1.y);
        c1.z = leaky(c1.z + b1.z); c1.w = leaky(c1.w + b1.w);
        *(float4*)(t1 + rg * HD + j0) = c1;
        __syncthreads();
        float4 c2 = gemm_row<HD>(t1 + rg * HD, wb + W_VW2T, jg);
        float4 b2 = *(const float4*)(wb + W_VB2 + j0);
        c2.x = tanhf(c2.x + b2.x); c2.y = tanhf(c2.y + b2.y);
        c2.z = tanhf(c2.z + b2.z); c2.w = tanhf(c2.w + b2.w);
        long o = (long)(r0 + rg) * HD + j0;
        *(float4*)(hv + o) = c2;
        *(float4*)(acc + o) = c2;
    } else {
        int r0 = (blockIdx.x - NV / 4) * 4;
        for (int i = t; i < 4 * BD; i += 128) xs[i] = bond[(long)r0 * BD + i];
        __syncthreads();
        float4 c1 = gemm_row<BD>(xs + rg * BD, wb + W_EW1T, jg);
        float4 b1 = *(const float4*)(wb + W_EB1 + j0);
        c1.x = leaky(c1.x + b1.x); c1.y = leaky(c1.y + b1.y);
        c1.z = leaky(c1.z + b1.z); c1.w = leaky(c1.w + b1.w);
        *(float4*)(t1 + rg * HD + j0) = c1;
        __syncthreads();
        float4 c2 = gemm_row<HD>(t1 + rg * HD, wb + W_EW2T, jg);
        float4 b2 = *(const float4*)(wb + W_EB2 + j0);
        c2.x = tanhf(c2.x + b2.x); c2.y = tanhf(c2.y + b2.y);
        c2.z = tanhf(c2.z + b2.z); c2.w = tanhf(c2.w + b2.w);
        *(float4*)(outf + (long)OUT_HE + (long)(r0 + rg) * ESTR + 2 * HD + j0) = c2;
    }
}

__global__ void edge_pass_k(const float* __restrict__ outf, const float* __restrict__ hv,
                            const int* __restrict__ src, const int* __restrict__ dst,
                            float* __restrict__ acc) {
    int t = threadIdx.x;
    int e = blockIdx.x * 2 + (t >> 7), j = t & 127;
    int s = clampv(src[e]), d = clampv(dst[e]);
    float v = outf[(long)OUT_HE + (long)e * ESTR + 2 * HD + j] + hv[(long)d * HD + j];
    v = v > 0.f ? v : 0.f;
    atomicAdd(acc + (long)s * HD + j, v);
}

__global__ void mlp_k(const float* __restrict__ accin, const float* __restrict__ wb,
                      float* __restrict__ hv, float* __restrict__ accout, int l,
                      float* hv_out) {
    __shared__ __align__(16) float xs[4 * HD];
    int t = threadIdx.x, r0 = blockIdx.x * 4;
    for (int i = t; i < 4 * HD; i += 128) xs[i] = accin[(long)r0 * HD + i];
    __syncthreads();
    int jg = t & 31, rg = t >> 5, j0 = jg * 4;
    float4 c = gemm_row<HD>(xs + rg * HD, wb + W_MWT + l * 16384, jg);
    float4 b = *(const float4*)(wb + W_MB + l * HD + j0);
    c.x = leaky(c.x + b.x); c.y = leaky(c.y + b.y);
    c.z = leaky(c.z + b.z); c.w = leaky(c.w + b.w);
    long o = (long)(r0 + rg) * HD + j0;
    *(float4*)(hv + o) = c;
    *(float4*)(accout + o) = c;
    if (hv_out) *(float4*)(hv_out + o) = c;
}

__global__ void out_he_k(const float* __restrict__ hv,
                         const int* __restrict__ src, const int* __restrict__ dst,
                         float* __restrict__ outf) {
    int e = blockIdx.x, t = threadIdx.x, j0 = t * 2;
    int s = clampv(src[e]), d = clampv(dst[e]);
    float2 a = *(const float2*)(hv + (long)s * HD + j0);
    float2 b = *(const float2*)(hv + (long)d * HD + j0);
    float* base = outf + (long)OUT_HE + (long)e * ESTR;
    *(float2*)(base + j0) = a;
    *(float2*)(base + HD + j0) = b;
}

extern "C" void kernel_launch(void* const* d_in, const int* in_sizes, int n_in,
                              void* d_out, int out_size, void* d_ws, size_t ws_size,
                              hipStream_t stream) {
    char* ws = (char*)d_ws;
    int*   srcv = (int*)ws;                         // NE
    int*   dstv = srcv + NE;                        // NE
    float* wb   = (float*)(ws + 2 * NE * 4);        // W_TOTAL floats
    float* hv   = wb + W_TOTAL;                     // NV*HD
    float* acc  = hv + (long)NV * HD;               // NV*HD

    MegaParams p;
    p.vew1 = (const uint4*)d_in[2];  p.vew2 = (const uint4*)d_in[3];
    p.atom = (const float*)d_in[0];  p.bond = (const float*)d_in[1];
    p.vW1 = (const float*)d_in[4];   p.vW2 = (const float*)d_in[6];
    p.eW1 = (const float*)d_in[8];   p.eW2 = (const float*)d_in[10];
    p.mW  = (const float*)d_in[12];
    p.vb1 = (const float*)d_in[5];   p.vb2 = (const float*)d_in[7];
    p.eb1 = (const float*)d_in[9];   p.eb2 = (const float*)d_in[11];
    p.mb  = (const float*)d_in[13];
    p.srcv = srcv; p.dstv = dstv; p.wb = wb; p.hv = hv; p.acc = acc;
    p.outf = (float*)d_out;

    // size coop grid from a runtime occupancy query (host-only, graph-safe)
    int maxb = 0;
    hipError_t qe = hipOccupancyMaxActiveBlocksPerMultiprocessor(
        &maxb, (const void*)mega_k, BLK, 0);
    int grid = (qe == hipSuccess) ? maxb * 256 : 0;   // 256 CUs on MI355X
    if (grid > 1024) grid = 1024;

    hipError_t le = hipErrorUnknown;
    if (grid >= 256) {
        void* args[] = { &p };
        le = hipLaunchCooperativeKernel((void*)mega_k, dim3(grid), dim3(BLK),
                                        args, 0, stream);
    }
    if (le != hipSuccess) {
        // r8-proven fallback sequence
        extract_prep_k<<<2048 + (W_TOTAL + 255) / 256, 256, 0, stream>>>(
            p.vew1, p.vew2, srcv, dstv, p.vW1, p.vW2, p.eW1, p.eW2, p.mW,
            p.vb1, p.vb2, p.eb1, p.eb2, p.mb, wb);
        vlin_elin_k<<<3 * NV / 4, 128, 0, stream>>>(p.atom, p.bond, wb, hv, acc, p.outf);
        for (int l = 0; l < NL; l++) {
            edge_pass_k<<<NE / 2, 256, 0, stream>>>(p.outf, hv, srcv, dstv, acc);
            mlp_k<<<NV / 4, 128, 0, stream>>>(acc, wb, hv, acc, l,
                                              (l == NL - 1) ? p.outf : nullptr);
        }
        out_he_k<<<NE, 64, 0, stream>>>(hv, srcv, dstv, p.outf);
    }
}

// Round 11
// 415.678 us; speedup vs baseline: 2.4962x; 2.4962x over previous
//
#include <hip/hip_runtime.h>
#include <hip/hip_bf16.h>

#define NV 4096
#define NE 8192
#define AD 64      // ATOM_DIM
#define BD 32      // BOND_DIM_P1
#define HD 128     // H
#define NL 4       // N_LAYER
#define DEGCAP 32  // adjacency bucket capacity (lambda=2 Poisson, max deg << 32)

// Everything is fp32 (proven r6-r8/r10).

__device__ __forceinline__ float leaky(float x) { return x > 0.f ? x : 0.01f * x; }
__device__ __forceinline__ int clampv(int x) { return min(max(x, 0), NV - 1); }

// ---- fp32 weight scratch layout (float offsets), proven r3/r6-r8 ----
#define W_VW1T 0           // [64][128]   Wt[k][j] = W[j][k]
#define W_VW2T 8192        // [128][128]
#define W_EW1T 24576       // [32][128]
#define W_EW2T 28672       // [128][128]
#define W_MWT  45056       // [4][128][128]
#define W_VB1  110592
#define W_VB2  110720
#define W_EB1  110848
#define W_EB2  110976
#define W_MB   111104      // [4][128]
#define W_TOTAL 111616     // = 436 * 256 exactly

// ---- out layout (float offsets): [hv 524288][per-edge 384: src|dst|he] ----
#define OUT_HE 524288
#define ESTR   384

// ---- ws layout (byte offsets) ----
#define WS_SRC 0            // NE ints
#define WS_DST 32768        // NE ints
#define WS_DEG 65536        // NV ints
#define WS_ADJ 81920        // NV*DEGCAP ints (512 KB)
#define WS_WB  606208       // W_TOTAL floats
#define WS_HVA 1052672      // NV*HD floats (2 MB)
#define WS_HVB 3149824      // NV*HD floats (2 MB)

// ---------------------------------------------------------------------------
// Fused extract + weight-prep + deg-zero (r8-proven bodies + trivial zeroing)
// blocks [0,2048): extract; [2048,2484): weight prep; [2484,2500): deg = 0
// ---------------------------------------------------------------------------
__global__ __launch_bounds__(256, 3)
void extract_prep_k(const uint4* __restrict__ vew1, const uint4* __restrict__ vew2,
                    int* __restrict__ srcv, int* __restrict__ dstv,
                    const float* __restrict__ vW1, const float* __restrict__ vW2,
                    const float* __restrict__ eW1, const float* __restrict__ eW2,
                    const float* __restrict__ mW,
                    const float* __restrict__ vb1, const float* __restrict__ vb2,
                    const float* __restrict__ eb1, const float* __restrict__ eb2,
                    const float* __restrict__ mb, float* __restrict__ wb,
                    int* __restrict__ deg) {
    int blk = blockIdx.x, t = threadIdx.x;
    if (blk < 2048) {
        const uint4* m = (blk < 1024) ? vew1 : vew2;
        int* out = (blk < 1024) ? srcv : dstv;
        int r0 = (blk & 1023) * 4;
        const uint4* p = m + (long)r0 * 2048;
#pragma unroll
        for (int b = 0; b < 2; b++) {
            uint4 u[16];
            unsigned o[16];
            int base = b * 4096 + t;
#pragma unroll
            for (int k = 0; k < 16; k++) u[k] = p[base + k * 256];
#pragma unroll
            for (int k = 0; k < 16; k++) o[k] = u[k].x | u[k].y | u[k].z | u[k].w;
            unsigned any = 0;
#pragma unroll
            for (int k = 0; k < 16; k++) any |= o[k];
            if (any == 0u) continue;
#pragma unroll
            for (int k = 0; k < 16; k++) {
                if (o[k] == 0u) continue;
                int i = base + k * 256;
                int row = r0 + (i >> 11);
                int col = (i << 2) & (NE - 1);
                if (u[k].x) out[col + 0] = row;
                if (u[k].y) out[col + 1] = row;
                if (u[k].z) out[col + 2] = row;
                if (u[k].w) out[col + 3] = row;
            }
        }
    } else if (blk < 2484) {
        int i = (blk - 2048) * 256 + t;
        if (i >= W_TOTAL) return;
        float v;
        if (i < W_VW2T)      { int q = i;          int k = q / 128, j = q % 128; v = vW1[(long)j * AD + k]; }
        else if (i < W_EW1T) { int q = i - W_VW2T; int k = q / 128, j = q % 128; v = vW2[(long)j * HD + k]; }
        else if (i < W_EW2T) { int q = i - W_EW1T; int k = q / 128, j = q % 128; v = eW1[(long)j * BD + k]; }
        else if (i < W_MWT)  { int q = i - W_EW2T; int k = q / 128, j = q % 128; v = eW2[(long)j * HD + k]; }
        else if (i < W_VB1)  { int q = i - W_MWT;  int l = q / 16384, r = q % 16384;
                               int k = r / 128, j = r % 128;
                               v = mW[(long)l * 16384 + (long)j * HD + k]; }
        else if (i < W_VB2)  v = vb1[i - W_VB1];
        else if (i < W_EB1)  v = vb2[i - W_VB2];
        else if (i < W_EB2)  v = eb1[i - W_EB1];
        else if (i < W_MB)   v = eb2[i - W_EB2];
        else                 v = mb[i - W_MB];
        wb[i] = v;
    } else {
        int i = (blk - 2484) * 256 + t;
        if (i < NV) deg[i] = 0;
    }
}

// micro-GEMM (proven r3/r6-r8)
template<int K>
__device__ __forceinline__ float4 gemm_row(const float* __restrict__ xrow,
                                           const float* __restrict__ Wt, int jg) {
    float4 c = make_float4(0.f, 0.f, 0.f, 0.f);
    const float4* W4 = (const float4*)Wt;
#pragma unroll 8
    for (int k = 0; k < K; k += 4) {
        float4 xv = *(const float4*)(xrow + k);
        float4 w0 = W4[(k + 0) * 32 + jg];
        float4 w1 = W4[(k + 1) * 32 + jg];
        float4 w2 = W4[(k + 2) * 32 + jg];
        float4 w3 = W4[(k + 3) * 32 + jg];
        c.x = fmaf(xv.x, w0.x, fmaf(xv.y, w1.x, fmaf(xv.z, w2.x, fmaf(xv.w, w3.x, c.x))));
        c.y = fmaf(xv.x, w0.y, fmaf(xv.y, w1.y, fmaf(xv.z, w2.y, fmaf(xv.w, w3.y, c.y))));
        c.z = fmaf(xv.x, w0.z, fmaf(xv.y, w1.z, fmaf(xv.z, w2.z, fmaf(xv.w, w3.z, c.z))));
        c.w = fmaf(xv.x, w0.w, fmaf(xv.y, w1.w, fmaf(xv.z, w2.w, fmaf(xv.w, w3.w, c.w))));
    }
    return c;
}

// ---------------------------------------------------------------------------
// fused input MLPs (r8-proven) + adjacency-bucket fill in spare blocks
// blocks [0,1024): node rows -> hvA; [1024,3072): edge rows -> he out slot
// blocks [3072,3136): adj fill: deg/adj from srcv (extract_prep completed)
// ---------------------------------------------------------------------------
__global__ void vlin_elin_k(const float* __restrict__ atom, const float* __restrict__ bond,
                            const float* __restrict__ wb,
                            float* __restrict__ hv, float* __restrict__ outf,
                            const int* __restrict__ srcv,
                            int* __restrict__ deg, int* __restrict__ adj) {
    __shared__ __align__(16) float xs[4 * AD];
    __shared__ __align__(16) float t1[4 * HD];
    int t = threadIdx.x, jg = t & 31, rg = t >> 5, j0 = jg * 4;
    if (blockIdx.x < NV / 4) {
        int r0 = blockIdx.x * 4;
        for (int i = t; i < 4 * AD; i += 128) xs[i] = atom[(long)r0 * AD + i];
        __syncthreads();
        float4 c1 = gemm_row<AD>(xs + rg * AD, wb + W_VW1T, jg);
        float4 b1 = *(const float4*)(wb + W_VB1 + j0);
        c1.x = leaky(c1.x + b1.x); c1.y = leaky(c1.y + b1.y);
        c1.z = leaky(c1.z + b1.z); c1.w = leaky(c1.w + b1.w);
        *(float4*)(t1 + rg * HD + j0) = c1;
        __syncthreads();
        float4 c2 = gemm_row<HD>(t1 + rg * HD, wb + W_VW2T, jg);
        float4 b2 = *(const float4*)(wb + W_VB2 + j0);
        c2.x = tanhf(c2.x + b2.x); c2.y = tanhf(c2.y + b2.y);
        c2.z = tanhf(c2.z + b2.z); c2.w = tanhf(c2.w + b2.w);
        *(float4*)(hv + (long)(r0 + rg) * HD + j0) = c2;
    } else if (blockIdx.x < 3 * NV / 4) {
        int r0 = (blockIdx.x - NV / 4) * 4;
        for (int i = t; i < 4 * BD; i += 128) xs[i] = bond[(long)r0 * BD + i];
        __syncthreads();
        float4 c1 = gemm_row<BD>(xs + rg * BD, wb + W_EW1T, jg);
        float4 b1 = *(const float4*)(wb + W_EB1 + j0);
        c1.x = leaky(c1.x + b1.x); c1.y = leaky(c1.y + b1.y);
        c1.z = leaky(c1.z + b1.z); c1.w = leaky(c1.w + b1.w);
        *(float4*)(t1 + rg * HD + j0) = c1;
        __syncthreads();
        float4 c2 = gemm_row<HD>(t1 + rg * HD, wb + W_EW2T, jg);
        float4 b2 = *(const float4*)(wb + W_EB2 + j0);
        c2.x = tanhf(c2.x + b2.x); c2.y = tanhf(c2.y + b2.y);
        c2.z = tanhf(c2.z + b2.z); c2.w = tanhf(c2.w + b2.w);
        *(float4*)(outf + (long)OUT_HE + (long)(r0 + rg) * ESTR + 2 * HD + j0) = c2;
    } else {
        int e = (blockIdx.x - 3 * NV / 4) * 128 + t;   // 64 blocks x 128 = NE
        if (e < NE) {
            int s = clampv(srcv[e]);
            int p = atomicAdd(&deg[s], 1);
            if (p < DEGCAP) adj[s * DEGCAP + p] = e;
        }
    }
}

// ---------------------------------------------------------------------------
// fused layer (CSR-gather, no atomics):
// x[r] = hv[r] + sum_{e in adj[r]} relu(he[e] + hv[dst[e]]);
// hv'[r] = leaky(W_l x[r] + b_l);  l==3 also writes out-hv section.
// ---------------------------------------------------------------------------
__global__ void layer_k(const float* __restrict__ hvin, const float* __restrict__ wb,
                        const int* __restrict__ deg, const int* __restrict__ adj,
                        const int* __restrict__ dstv, const float* __restrict__ outf,
                        float* __restrict__ hvout, int l, float* hv_out) {
    __shared__ __align__(16) float xs[4 * HD];
    int t = threadIdx.x, jg = t & 31, rg = t >> 5, j0 = jg * 4;
    int r = blockIdx.x * 4 + rg;
    float4 x = *(const float4*)(hvin + (long)r * HD + j0);
    int dn = min(deg[r], DEGCAP);
    const int* al = adj + r * DEGCAP;
    for (int i = 0; i < dn; i++) {
        int e = al[i]; e = max(0, min(e, NE - 1));
        int d = clampv(dstv[e]);
        float4 he = *(const float4*)(outf + (long)OUT_HE + (long)e * ESTR + 2 * HD + j0);
        float4 hd = *(const float4*)(hvin + (long)d * HD + j0);
        float s0 = he.x + hd.x, s1 = he.y + hd.y;
        float s2 = he.z + hd.z, s3 = he.w + hd.w;
        x.x += s0 > 0.f ? s0 : 0.f; x.y += s1 > 0.f ? s1 : 0.f;
        x.z += s2 > 0.f ? s2 : 0.f; x.w += s3 > 0.f ? s3 : 0.f;
    }
    *(float4*)(xs + rg * HD + j0) = x;
    __syncthreads();
    float4 c = gemm_row<HD>(xs + rg * HD, wb + W_MWT + l * 16384, jg);
    float4 b = *(const float4*)(wb + W_MB + l * HD + j0);
    c.x = leaky(c.x + b.x); c.y = leaky(c.y + b.y);
    c.z = leaky(c.z + b.z); c.w = leaky(c.w + b.w);
    long o = (long)r * HD + j0;
    *(float4*)(hvout + o) = c;
    if (hv_out) *(float4*)(hv_out + o) = c;
}

// gather sections: out[e] = [hv[src[e]] | hv[dst[e]] | he(already in place)]
__global__ void out_he_k(const float* __restrict__ hv,
                         const int* __restrict__ src, const int* __restrict__ dst,
                         float* __restrict__ outf) {
    int e = blockIdx.x, t = threadIdx.x, j0 = t * 2;
    int s = clampv(src[e]), d = clampv(dst[e]);
    float2 a = *(const float2*)(hv + (long)s * HD + j0);
    float2 b = *(const float2*)(hv + (long)d * HD + j0);
    float* base = outf + (long)OUT_HE + (long)e * ESTR;
    *(float2*)(base + j0) = a;
    *(float2*)(base + HD + j0) = b;
}

extern "C" void kernel_launch(void* const* d_in, const int* in_sizes, int n_in,
                              void* d_out, int out_size, void* d_ws, size_t ws_size,
                              hipStream_t stream) {
    char* ws = (char*)d_ws;
    int*   srcv = (int*)(ws + WS_SRC);
    int*   dstv = (int*)(ws + WS_DST);
    int*   deg  = (int*)(ws + WS_DEG);
    int*   adj  = (int*)(ws + WS_ADJ);
    float* wb   = (float*)(ws + WS_WB);
    float* hvA  = (float*)(ws + WS_HVA);
    float* hvB  = (float*)(ws + WS_HVB);
    float* outf = (float*)d_out;

    extract_prep_k<<<2500, 256, 0, stream>>>(
        (const uint4*)d_in[2], (const uint4*)d_in[3], srcv, dstv,
        (const float*)d_in[4], (const float*)d_in[6], (const float*)d_in[8],
        (const float*)d_in[10], (const float*)d_in[12],
        (const float*)d_in[5], (const float*)d_in[7], (const float*)d_in[9],
        (const float*)d_in[11], (const float*)d_in[13], wb, deg);
    vlin_elin_k<<<3 * NV / 4 + NE / 128, 128, 0, stream>>>(
        (const float*)d_in[0], (const float*)d_in[1], wb, hvA, outf, srcv, deg, adj);

    // ping-pong: A->B->A->B->A (final hv in A)
    layer_k<<<NV / 4, 128, 0, stream>>>(hvA, wb, deg, adj, dstv, outf, hvB, 0, nullptr);
    layer_k<<<NV / 4, 128, 0, stream>>>(hvB, wb, deg, adj, dstv, outf, hvA, 1, nullptr);
    layer_k<<<NV / 4, 128, 0, stream>>>(hvA, wb, deg, adj, dstv, outf, hvB, 2, nullptr);
    layer_k<<<NV / 4, 128, 0, stream>>>(hvB, wb, deg, adj, dstv, outf, hvA, 3, outf);

    out_he_k<<<NE, 64, 0, stream>>>(hvA, srcv, dstv, outf);
}